// Round 1
// baseline (473.571 us; speedup 1.0000x reference)
//
#include <hip/hip_runtime.h>

typedef unsigned short u16;
typedef unsigned int   u32;

typedef short  short8  __attribute__((ext_vector_type(8)));
typedef __bf16 bf16x8  __attribute__((ext_vector_type(8)));
typedef float  f32x4   __attribute__((ext_vector_type(4)));

#define S_LEN   2048
#define DM      1024
#define NHEAD   16
#define DK      64
#define BH_TOT  64
#define M_TOK   8192
#define KDIM    1024

// ---------- helpers ----------
__device__ __forceinline__ u16 f2bf(float f) {
    u32 u = __builtin_bit_cast(u32, f);
    u += 0x7FFFu + ((u >> 16) & 1u);      // RNE
    return (u16)(u >> 16);
}
__device__ __forceinline__ float bf2f(u16 h) {
    u32 u = ((u32)h) << 16;
    return __builtin_bit_cast(float, u);
}
__device__ __forceinline__ f32x4 mfma_bf16(short8 a, short8 b, f32x4 c) {
    return __builtin_amdgcn_mfma_f32_16x16x32_bf16(
        __builtin_bit_cast(bf16x8, a), __builtin_bit_cast(bf16x8, b), c, 0, 0, 0);
}
// async global->LDS, 16B per lane. LDS dest semantics: wave-uniform base + lane*16;
// we pass per-lane ptr = base + lane*16 which is consistent either way.
__device__ __forceinline__ void gl_lds16(const void* g, void* l) {
    __builtin_amdgcn_global_load_lds(
        (const __attribute__((address_space(1))) u32*)g,
        (__attribute__((address_space(3))) u32*)l, 16, 0, 0);
}

// ---------- fp32 -> bf16 convert (x4 vectorized) ----------
__global__ void cvt_bf16_v4(const float4* __restrict__ in, uint2* __restrict__ out, int n4) {
    int i = blockIdx.x * 256 + threadIdx.x;
    if (i >= n4) return;
    float4 f = in[i];
    uint2 o;
    o.x = (u32)f2bf(f.x) | ((u32)f2bf(f.y) << 16);
    o.y = (u32)f2bf(f.z) | ((u32)f2bf(f.w) << 16);
    out[i] = o;
}

// ---------- RoPE (in-place on Q,K; one u32 = one even/odd pair) ----------
__global__ void rope_qk(u16* __restrict__ Qb, u16* __restrict__ Kb) {
    int idx = blockIdx.x * 256 + threadIdx.x;           // 0 .. 2*64*2048*32-1
    const int PER = BH_TOT * S_LEN * 32;                // 4194304 pairs per buffer
    u16* T = (idx < PER) ? Qb : Kb;
    int i2 = (idx < PER) ? idx : idx - PER;
    int i  = i2 & 31;                                   // freq index 0..31
    int s  = (i2 >> 5) & 2047;
    int bh = i2 >> 16;                                  // 2048*32 = 65536
    u32* p = (u32*)T + (size_t)(bh * S_LEN + s) * 32 + i;
    u32 v = *p;
    float e = bf2f((u16)(v & 0xFFFF));
    float o = bf2f((u16)(v >> 16));
    // inv_freq = 10000^(-i/32) = exp(-i * ln(10000)/32)
    float inv = expf(-(float)i * 0.287823136624255f);
    float ang = (float)s * inv;
    float sn = sinf(ang), cs = cosf(ang);
    float e2 = e * cs - o * sn;
    float o2 = e * sn + o * cs;
    *p = (u32)f2bf(e2) | ((u32)f2bf(o2) << 16);
}

// ---------- NT GEMM: C[m][n] = sum_k A[m][k]*W[n][k], K=1024, bf16 in, fp32 acc ----------
// BM=BN=128, BK=32, 256 thr (4 waves), wave -> 64x64, acc 4x4 of 16x16x32 MFMA.
// MODE 0: N=3072 fused QKV epilogue (Q,K -> [BH][S][64], V -> transposed [BH][64][S])
// MODE 1: plain fp32 store to out[m*1024+n]
template <int MODE>
__global__ __launch_bounds__(256)
void gemm_nt(const u16* __restrict__ A, const u16* __restrict__ Bw,
             u16* __restrict__ oQ, u16* __restrict__ oK, u16* __restrict__ oVt,
             float* __restrict__ oF) {
    __shared__ u16 As[128 * 32];
    __shared__ u16 Bs[128 * 32];
    const int tid  = threadIdx.x;
    const int wave = tid >> 6, lane = tid & 63;
    const int quad = lane >> 4, l15 = lane & 15;
    const int wr = wave >> 1, wc = wave & 1;
    const int mbase = blockIdx.y * 128;
    const int nbase = blockIdx.x * 128;

    f32x4 acc[4][4];
#pragma unroll
    for (int i = 0; i < 4; i++)
#pragma unroll
        for (int j = 0; j < 4; j++) acc[i][j] = (f32x4)0.0f;

    // staging: 8 chunks of 1024B per tile; wave w does chunks 2w, 2w+1
    const int c0 = wave * 2, c1 = wave * 2 + 1;
    const int srow0 = c0 * 16 + (lane >> 2);
    const int srow1 = c1 * 16 + (lane >> 2);
    const int scolb = (lane & 3) * 16;   // byte offset within the 64B row-slice

    for (int kk = 0; kk < KDIM; kk += 32) {
        gl_lds16((const char*)(A  + (size_t)(mbase + srow0) * KDIM + kk) + scolb,
                 (char*)As + c0 * 1024 + lane * 16);
        gl_lds16((const char*)(A  + (size_t)(mbase + srow1) * KDIM + kk) + scolb,
                 (char*)As + c1 * 1024 + lane * 16);
        gl_lds16((const char*)(Bw + (size_t)(nbase + srow0) * KDIM + kk) + scolb,
                 (char*)Bs + c0 * 1024 + lane * 16);
        gl_lds16((const char*)(Bw + (size_t)(nbase + srow1) * KDIM + kk) + scolb,
                 (char*)Bs + c1 * 1024 + lane * 16);
        __syncthreads();

        short8 af[4], bf[4];
#pragma unroll
        for (int mt = 0; mt < 4; mt++)
            af[mt] = *(const short8*)&As[(wr * 64 + mt * 16 + l15) * 32 + quad * 8];
#pragma unroll
        for (int nt = 0; nt < 4; nt++)
            bf[nt] = *(const short8*)&Bs[(wc * 64 + nt * 16 + l15) * 32 + quad * 8];
#pragma unroll
        for (int mt = 0; mt < 4; mt++)
#pragma unroll
            for (int nt = 0; nt < 4; nt++)
                acc[mt][nt] = mfma_bf16(af[mt], bf[nt], acc[mt][nt]);
        __syncthreads();
    }

    // epilogue. C layout: col = l15, row = quad*4 + reg
#pragma unroll
    for (int mt = 0; mt < 4; mt++) {
#pragma unroll
        for (int nt = 0; nt < 4; nt++) {
            const int n  = nbase + wc * 64 + nt * 16 + l15;
            const int mb = mbase + wr * 64 + mt * 16 + quad * 4;
            f32x4 v = acc[mt][nt];
            if (MODE == 0) {
                const int proj = n >> 10;       // 0=Q 1=K 2=V
                const int e = n & 1023;
                const int h = e >> 6, d = e & 63;
                if (proj == 2) {
                    // Vt[bh][d][s]; 4 regs = 4 consecutive s -> one 8B store
                    const int b = mb >> 11, s = mb & 2047;
                    const int bh = b * NHEAD + h;
                    uint2 pk;
                    pk.x = (u32)f2bf(v[0]) | ((u32)f2bf(v[1]) << 16);
                    pk.y = (u32)f2bf(v[2]) | ((u32)f2bf(v[3]) << 16);
                    *(uint2*)&oVt[((size_t)bh * DK + d) * S_LEN + s] = pk;
                } else {
                    u16* dst = (proj == 0) ? oQ : oK;
#pragma unroll
                    for (int r = 0; r < 4; r++) {
                        const int m = mb + r;
                        const int b = m >> 11, s = m & 2047;
                        const int bh = b * NHEAD + h;
                        dst[((size_t)bh * S_LEN + s) * DK + d] = f2bf(v[r]);
                    }
                }
            } else {
#pragma unroll
                for (int r = 0; r < 4; r++)
                    oF[(size_t)(mb + r) * DM + n] = v[r];
            }
        }
    }
}

// ---------- causal flash attention ----------
// grid (S/64, BH); 256 thr = 4 waves; wave owns 16 q-rows.
__global__ __launch_bounds__(256)
void flash_attn(const u16* __restrict__ Q, const u16* __restrict__ K,
                const u16* __restrict__ Vt, u16* __restrict__ Oc) {
    __shared__ u16 Ks[64 * 64];        // [sk][dk]
    __shared__ u16 Vs[64 * 64];        // [dk][sk]  (V transposed)
    __shared__ u16 Ps[4][16 * 72];     // per-wave P, row pad 64->72 (bank spread)
    const int qt = blockIdx.x, bh = blockIdx.y;
    const int tid  = threadIdx.x;
    const int wave = tid >> 6, lane = tid & 63;
    const int quad = lane >> 4, l15 = lane & 15;
    const size_t headQK = (size_t)bh * S_LEN * DK;
    const size_t headVt = (size_t)bh * DK * S_LEN;

    // Q A-fragments: lane holds Q[m=l15][k=quad*8+j], ks=0/1 for dk 0..31 / 32..63
    const int qrow = qt * 64 + wave * 16 + l15;
    short8 qf0 = *(const short8*)&Q[headQK + (size_t)qrow * DK + quad * 8];
    short8 qf1 = *(const short8*)&Q[headQK + (size_t)qrow * DK + 32 + quad * 8];

    float m_st[4], l_st[4];
    f32x4 oacc[4];
#pragma unroll
    for (int r = 0; r < 4; r++) { m_st[r] = -__builtin_inff(); l_st[r] = 0.f; }
#pragma unroll
    for (int n = 0; n < 4; n++) oacc[n] = (f32x4)0.0f;

    for (int kt = 0; kt <= qt; kt++) {
        // stage K tile (contiguous 8KB) and Vt tile (64 d-rows x 128B)
        {
            const int c0 = wave * 2, c1 = c0 + 1;
            const u16* gK = K + headQK + (size_t)kt * 64 * DK;
            gl_lds16((const char*)gK + c0 * 1024 + lane * 16, (char*)Ks + c0 * 1024 + lane * 16);
            gl_lds16((const char*)gK + c1 * 1024 + lane * 16, (char*)Ks + c1 * 1024 + lane * 16);
            const int d0 = c0 * 8 + (lane >> 3), d1 = c1 * 8 + (lane >> 3);
            const int sko = (lane & 7) * 8;
            gl_lds16((const char*)(Vt + headVt + (size_t)d0 * S_LEN + kt * 64 + sko),
                     (char*)Vs + c0 * 1024 + lane * 16);
            gl_lds16((const char*)(Vt + headVt + (size_t)d1 * S_LEN + kt * 64 + sko),
                     (char*)Vs + c1 * 1024 + lane * 16);
        }
        __syncthreads();

        // scores S[16 q][64 k], scaled by 1/sqrt(64)
        f32x4 sc[4];
#pragma unroll
        for (int nt = 0; nt < 4; nt++) {
            short8 kf0 = *(const short8*)&Ks[(nt * 16 + l15) * 64 + quad * 8];
            short8 kf1 = *(const short8*)&Ks[(nt * 16 + l15) * 64 + 32 + quad * 8];
            f32x4 z = (f32x4)0.0f;
            z = mfma_bf16(qf0, kf0, z);
            z = mfma_bf16(qf1, kf1, z);
#pragma unroll
            for (int r = 0; r < 4; r++) z[r] *= 0.125f;
            sc[nt] = z;
        }
        if (kt == qt) {   // diagonal tile: causal mask
#pragma unroll
            for (int nt = 0; nt < 4; nt++) {
                const int kc = kt * 64 + nt * 16 + l15;
#pragma unroll
                for (int r = 0; r < 4; r++) {
                    const int qr = qt * 64 + wave * 16 + quad * 4 + r;
                    if (kc > qr) sc[nt][r] = -__builtin_inff();
                }
            }
        }
        // online softmax. rows live at quad*4+r, replicated across the quad's 16 lanes
        float alpha[4], rs[4];
#pragma unroll
        for (int r = 0; r < 4; r++) {
            float v = fmaxf(fmaxf(sc[0][r], sc[1][r]), fmaxf(sc[2][r], sc[3][r]));
            v = fmaxf(v, __shfl_xor(v, 1));
            v = fmaxf(v, __shfl_xor(v, 2));
            v = fmaxf(v, __shfl_xor(v, 4));
            v = fmaxf(v, __shfl_xor(v, 8));
            float mn = fmaxf(m_st[r], v);
            alpha[r] = __expf(m_st[r] - mn);
            m_st[r] = mn;
            rs[r] = 0.f;
        }
        u16* pw = &Ps[wave][0];
#pragma unroll
        for (int nt = 0; nt < 4; nt++) {
#pragma unroll
            for (int r = 0; r < 4; r++) {
                float p = __expf(sc[nt][r] - m_st[r]);
                rs[r] += p;
                pw[(quad * 4 + r) * 72 + nt * 16 + l15] = f2bf(p);
            }
        }
#pragma unroll
        for (int r = 0; r < 4; r++) {
            float v = rs[r];
            v += __shfl_xor(v, 1);
            v += __shfl_xor(v, 2);
            v += __shfl_xor(v, 4);
            v += __shfl_xor(v, 8);
            l_st[r] = alpha[r] * l_st[r] + v;
        }
#pragma unroll
        for (int n = 0; n < 4; n++)
#pragma unroll
            for (int r = 0; r < 4; r++) oacc[n][r] *= alpha[r];
        // PV: A = P (LDS round-trip, same-wave DS ordering), B = V via Vt rows
#pragma unroll
        for (int ks = 0; ks < 2; ks++) {
            short8 pf = *(const short8*)&pw[l15 * 72 + ks * 32 + quad * 8];
#pragma unroll
            for (int nt2 = 0; nt2 < 4; nt2++) {
                short8 vf = *(const short8*)&Vs[(nt2 * 16 + l15) * 64 + ks * 32 + quad * 8];
                oacc[nt2] = mfma_bf16(pf, vf, oacc[nt2]);
            }
        }
        __syncthreads();
    }
    // epilogue: O/l -> attn[b][s][h*64+d] bf16
    const int b = bh >> 4, h = bh & 15;
#pragma unroll
    for (int r = 0; r < 4; r++) {
        const float inv = 1.0f / l_st[r];
        const int s = qt * 64 + wave * 16 + quad * 4 + r;
#pragma unroll
        for (int nt2 = 0; nt2 < 4; nt2++)
            Oc[((size_t)(b * S_LEN + s)) * DM + h * 64 + nt2 * 16 + l15] =
                f2bf(oacc[nt2][r] * inv);
    }
}

// ---------- workspace layout (u16 elements), total 72 MB ----------
// X_BF [8192*1024] (reused for attn output after QKV GEMM consumes it)
// WCAT [3*1024*1024]  WO [1024*1024]  QB/KB [64*2048*64 each]  VT [64*64*2048]
#define OFF_XBF  ((size_t)0)
#define OFF_WCAT ((size_t)8388608)
#define OFF_WO   ((size_t)11534336)
#define OFF_QB   ((size_t)12582912)
#define OFF_KB   ((size_t)20971520)
#define OFF_VT   ((size_t)29360128)

extern "C" void kernel_launch(void* const* d_in, const int* in_sizes, int n_in,
                              void* d_out, int out_size, void* d_ws, size_t ws_size,
                              hipStream_t stream) {
    const float* x  = (const float*)d_in[0];
    const float* Wq = (const float*)d_in[1];
    const float* Wk = (const float*)d_in[2];
    const float* Wv = (const float*)d_in[3];
    const float* Wo = (const float*)d_in[4];
    u16* ws  = (u16*)d_ws;
    u16* XBF = ws + OFF_XBF;
    u16* WCA = ws + OFF_WCAT;
    u16* WOB = ws + OFF_WO;
    u16* QB  = ws + OFF_QB;
    u16* KB  = ws + OFF_KB;
    u16* VT  = ws + OFF_VT;
    u16* AT  = XBF;   // reuse

    cvt_bf16_v4<<<8192, 256, 0, stream>>>((const float4*)x,  (uint2*)XBF, 2097152);
    cvt_bf16_v4<<<1024, 256, 0, stream>>>((const float4*)Wq, (uint2*)(WCA),            262144);
    cvt_bf16_v4<<<1024, 256, 0, stream>>>((const float4*)Wk, (uint2*)(WCA + 1048576),  262144);
    cvt_bf16_v4<<<1024, 256, 0, stream>>>((const float4*)Wv, (uint2*)(WCA + 2097152),  262144);
    cvt_bf16_v4<<<1024, 256, 0, stream>>>((const float4*)Wo, (uint2*)WOB, 262144);

    gemm_nt<0><<<dim3(24, 64), 256, 0, stream>>>(XBF, WCA, QB, KB, VT, nullptr);
    rope_qk<<<32768, 256, 0, stream>>>(QB, KB);
    flash_attn<<<dim3(32, 64), 256, 0, stream>>>(QB, KB, VT, AT);
    gemm_nt<1><<<dim3(8, 64), 256, 0, stream>>>(AT, WOB, nullptr, nullptr, nullptr,
                                                (float*)d_out);
}

// Round 2
// 326.959 us; speedup vs baseline: 1.4484x; 1.4484x over previous
//
#include <hip/hip_runtime.h>

typedef unsigned short u16;
typedef unsigned int   u32;

typedef short  short8  __attribute__((ext_vector_type(8)));
typedef __bf16 bf16x8  __attribute__((ext_vector_type(8)));
typedef float  f32x4   __attribute__((ext_vector_type(4)));

#define S_LEN   2048
#define DM      1024
#define NHEAD   16
#define DK      64
#define BH_TOT  64
#define M_TOK   8192
#define KDIM    1024

// ---------- helpers ----------
__device__ __forceinline__ u16 f2bf(float f) {
    u32 u = __builtin_bit_cast(u32, f);
    u += 0x7FFFu + ((u >> 16) & 1u);      // RNE
    return (u16)(u >> 16);
}
__device__ __forceinline__ float bf2f(u16 h) {
    u32 u = ((u32)h) << 16;
    return __builtin_bit_cast(float, u);
}
__device__ __forceinline__ f32x4 mfma_bf16(short8 a, short8 b, f32x4 c) {
    return __builtin_amdgcn_mfma_f32_16x16x32_bf16(
        __builtin_bit_cast(bf16x8, a), __builtin_bit_cast(bf16x8, b), c, 0, 0, 0);
}
__device__ __forceinline__ void gl_lds16(const void* g, void* l) {
    __builtin_amdgcn_global_load_lds(
        (const __attribute__((address_space(1))) u32*)g,
        (__attribute__((address_space(3))) u32*)l, 16, 0, 0);
}

// ---------- fp32 -> bf16 convert (x4 vectorized) ----------
__global__ void cvt_bf16_v4(const float4* __restrict__ in, uint2* __restrict__ out, int n4) {
    int i = blockIdx.x * 256 + threadIdx.x;
    if (i >= n4) return;
    float4 f = in[i];
    uint2 o;
    o.x = (u32)f2bf(f.x) | ((u32)f2bf(f.y) << 16);
    o.y = (u32)f2bf(f.z) | ((u32)f2bf(f.w) << 16);
    out[i] = o;
}

// ---------- RoPE (in-place on Q,K; one u32 = one even/odd pair) ----------
__global__ void rope_qk(u16* __restrict__ Qb, u16* __restrict__ Kb) {
    int idx = blockIdx.x * 256 + threadIdx.x;           // 0 .. 2*64*2048*32-1
    const int PER = BH_TOT * S_LEN * 32;                // 4194304 pairs per buffer
    u16* T = (idx < PER) ? Qb : Kb;
    int i2 = (idx < PER) ? idx : idx - PER;
    int i  = i2 & 31;                                   // freq index 0..31
    int s  = (i2 >> 5) & 2047;
    int bh = i2 >> 16;                                  // 2048*32 = 65536
    u32* p = (u32*)T + (size_t)(bh * S_LEN + s) * 32 + i;
    u32 v = *p;
    float e = bf2f((u16)(v & 0xFFFF));
    float o = bf2f((u16)(v >> 16));
    float inv = expf(-(float)i * 0.287823136624255f);   // 10000^(-i/32)
    float ang = (float)s * inv;
    float sn = sinf(ang), cs = cosf(ang);
    float e2 = e * cs - o * sn;
    float o2 = e * sn + o * cs;
    *p = (u32)f2bf(e2) | ((u32)f2bf(o2) << 16);
}

// ---------- NT GEMM: C[m][n] = sum_k A[m][k]*W[n][k], K=1024, bf16 in, fp32 acc ----------
template <int MODE>
__global__ __launch_bounds__(256)
void gemm_nt(const u16* __restrict__ A, const u16* __restrict__ Bw,
             u16* __restrict__ oQ, u16* __restrict__ oK, u16* __restrict__ oVt,
             float* __restrict__ oF) {
    __shared__ u16 As[128 * 32];
    __shared__ u16 Bs[128 * 32];
    const int tid  = threadIdx.x;
    const int wave = tid >> 6, lane = tid & 63;
    const int quad = lane >> 4, l15 = lane & 15;
    const int wr = wave >> 1, wc = wave & 1;
    const int mbase = blockIdx.y * 128;
    const int nbase = blockIdx.x * 128;

    f32x4 acc[4][4];
#pragma unroll
    for (int i = 0; i < 4; i++)
#pragma unroll
        for (int j = 0; j < 4; j++) acc[i][j] = (f32x4)0.0f;

    const int c0 = wave * 2, c1 = wave * 2 + 1;
    const int srow0 = c0 * 16 + (lane >> 2);
    const int srow1 = c1 * 16 + (lane >> 2);
    const int scolb = (lane & 3) * 16;

    for (int kk = 0; kk < KDIM; kk += 32) {
        gl_lds16((const char*)(A  + (size_t)(mbase + srow0) * KDIM + kk) + scolb,
                 (char*)As + c0 * 1024 + lane * 16);
        gl_lds16((const char*)(A  + (size_t)(mbase + srow1) * KDIM + kk) + scolb,
                 (char*)As + c1 * 1024 + lane * 16);
        gl_lds16((const char*)(Bw + (size_t)(nbase + srow0) * KDIM + kk) + scolb,
                 (char*)Bs + c0 * 1024 + lane * 16);
        gl_lds16((const char*)(Bw + (size_t)(nbase + srow1) * KDIM + kk) + scolb,
                 (char*)Bs + c1 * 1024 + lane * 16);
        __syncthreads();

        short8 af[4], bf[4];
#pragma unroll
        for (int mt = 0; mt < 4; mt++)
            af[mt] = *(const short8*)&As[(wr * 64 + mt * 16 + l15) * 32 + quad * 8];
#pragma unroll
        for (int nt = 0; nt < 4; nt++)
            bf[nt] = *(const short8*)&Bs[(wc * 64 + nt * 16 + l15) * 32 + quad * 8];
#pragma unroll
        for (int mt = 0; mt < 4; mt++)
#pragma unroll
            for (int nt = 0; nt < 4; nt++)
                acc[mt][nt] = mfma_bf16(af[mt], bf[nt], acc[mt][nt]);
        __syncthreads();
    }

    // epilogue. C layout: col = l15, row = quad*4 + reg
#pragma unroll
    for (int mt = 0; mt < 4; mt++) {
#pragma unroll
        for (int nt = 0; nt < 4; nt++) {
            const int n  = nbase + wc * 64 + nt * 16 + l15;
            const int mb = mbase + wr * 64 + mt * 16 + quad * 4;
            f32x4 v = acc[mt][nt];
            if (MODE == 0) {
                const int proj = n >> 10;       // 0=Q 1=K 2=V
                const int e = n & 1023;
                const int h = e >> 6, d = e & 63;
                if (proj == 2) {
                    const int b = mb >> 11, s = mb & 2047;
                    const int bh = b * NHEAD + h;
                    uint2 pk;
                    pk.x = (u32)f2bf(v[0]) | ((u32)f2bf(v[1]) << 16);
                    pk.y = (u32)f2bf(v[2]) | ((u32)f2bf(v[3]) << 16);
                    *(uint2*)&oVt[((size_t)bh * DK + d) * S_LEN + s] = pk;
                } else {
                    u16* dst = (proj == 0) ? oQ : oK;
#pragma unroll
                    for (int r = 0; r < 4; r++) {
                        const int m = mb + r;
                        const int b = m >> 11, s = m & 2047;
                        const int bh = b * NHEAD + h;
                        dst[((size_t)bh * S_LEN + s) * DK + d] = f2bf(v[r]);
                    }
                }
            } else {
#pragma unroll
                for (int r = 0; r < 4; r++)
                    oF[(size_t)(mb + r) * DM + n] = v[r];
            }
        }
    }
}

// ---------- causal flash attention ----------
// grid (16, BH): block handles q-tiles qt=blockIdx.x and qt=31-blockIdx.x (uniform 33 k-tiles).
// 4 waves; wave owns 16 q-rows. K/V LDS uses XOR chunk swizzle (conflict-free b128 reads).
// Row-sum via MFMA against ones-fragment (lacc) instead of shuffle reduction.
__global__ __launch_bounds__(256)
void flash_attn(const u16* __restrict__ Q, const u16* __restrict__ K,
                const u16* __restrict__ Vt, u16* __restrict__ Oc) {
    __shared__ u16 Ks[64 * 64];
    __shared__ u16 Vs[64 * 64];
    __shared__ u16 Ps[4][16 * 68];     // stride 68 u16 = 34 dwords -> <=2-way banks
    const int bh = blockIdx.y;
    const int tid  = threadIdx.x;
    const int wave = tid >> 6, lane = tid & 63;
    const int quad = lane >> 4, l15 = lane & 15;
    const int x7 = l15 & 7;
    const size_t headQK = (size_t)bh * S_LEN * DK;
    const size_t headVt = (size_t)bh * DK * S_LEN;
    const int b = bh >> 4, h = bh & 15;
    const float SCL = 0.18033688011112042f;   // (1/8) * log2(e)

    short8 ones;
#pragma unroll
    for (int j = 0; j < 8; j++) ones[j] = (short)0x3F80;   // bf16 1.0

    // staging geometry: wave stages slabs 2w,2w+1 (8 rows x 8 chunks of 16B each)
    const int srow = wave * 16 + (lane >> 3);       // row (K) / d (Vt); +8 for slab 2
    const int scol = (lane & 7) ^ (lane >> 3);      // XOR-swizzled chunk column
    char* ldsK0 = (char*)Ks + wave * 2048 + lane * 16;
    char* ldsV0 = (char*)Vs + wave * 2048 + lane * 16;
    const int koff0 = (quad ^ x7) * 8;              // ks=0 chunk col, swizzled
    const int koff1 = ((4 + quad) ^ x7) * 8;        // ks=1
    u16* pw = &Ps[wave][0];

    for (int seg = 0; seg < 2; seg++) {
        const int qt = seg ? (31 - (int)blockIdx.x) : (int)blockIdx.x;
        const int qrow = qt * 64 + wave * 16 + l15;
        const short8 qf0 = *(const short8*)&Q[headQK + (size_t)qrow * DK + quad * 8];
        const short8 qf1 = *(const short8*)&Q[headQK + (size_t)qrow * DK + 32 + quad * 8];
        const u16* gK = K  + headQK + (size_t)srow * DK + scol * 8;
        const u16* gV = Vt + headVt + (size_t)srow * S_LEN + scol * 8;

        float m_st[4];
        f32x4 lacc = (f32x4)0.0f;
        f32x4 oacc[4];
#pragma unroll
        for (int r = 0; r < 4; r++) m_st[r] = -__builtin_inff();
#pragma unroll
        for (int n = 0; n < 4; n++) oacc[n] = (f32x4)0.0f;

        for (int kt = 0; kt <= qt; kt++) {
            gl_lds16(gK + (size_t)kt * 64 * DK,          ldsK0);
            gl_lds16(gK + (size_t)kt * 64 * DK + 8 * DK, ldsK0 + 1024);
            gl_lds16(gV + kt * 64,                       ldsV0);
            gl_lds16(gV + kt * 64 + 8 * S_LEN,           ldsV0 + 1024);
            __syncthreads();

            // scores (log2-scaled)
            f32x4 sc[4];
#pragma unroll
            for (int nt = 0; nt < 4; nt++) {
                const int rb = (nt * 16 + l15) * 64;
                short8 kf0 = *(const short8*)&Ks[rb + koff0];
                short8 kf1 = *(const short8*)&Ks[rb + koff1];
                f32x4 z = (f32x4)0.0f;
                z = mfma_bf16(qf0, kf0, z);
                z = mfma_bf16(qf1, kf1, z);
#pragma unroll
                for (int r = 0; r < 4; r++) z[r] *= SCL;
                sc[nt] = z;
            }
            if (kt == qt) {   // diagonal tile causal mask
#pragma unroll
                for (int nt = 0; nt < 4; nt++) {
                    const int kc = kt * 64 + nt * 16 + l15;
#pragma unroll
                    for (int r = 0; r < 4; r++) {
                        const int qr = qt * 64 + wave * 16 + quad * 4 + r;
                        if (kc > qr) sc[nt][r] = -__builtin_inff();
                    }
                }
            }
            // online max (quad-local 16-lane reduction)
            float alpha[4];
#pragma unroll
            for (int r = 0; r < 4; r++) {
                float v = fmaxf(fmaxf(sc[0][r], sc[1][r]), fmaxf(sc[2][r], sc[3][r]));
                v = fmaxf(v, __shfl_xor(v, 1));
                v = fmaxf(v, __shfl_xor(v, 2));
                v = fmaxf(v, __shfl_xor(v, 4));
                v = fmaxf(v, __shfl_xor(v, 8));
                float mn = fmaxf(m_st[r], v);
                alpha[r] = __builtin_amdgcn_exp2f(m_st[r] - mn);
                m_st[r] = mn;
            }
            // P = exp2(sc - m), to LDS (C-layout -> A-layout round trip)
#pragma unroll
            for (int nt = 0; nt < 4; nt++) {
#pragma unroll
                for (int r = 0; r < 4; r++) {
                    float p = __builtin_amdgcn_exp2f(sc[nt][r] - m_st[r]);
                    pw[(quad * 4 + r) * 68 + nt * 16 + l15] = f2bf(p);
                }
            }
            // rescale accumulators
#pragma unroll
            for (int n = 0; n < 4; n++)
#pragma unroll
                for (int r = 0; r < 4; r++) oacc[n][r] *= alpha[r];
#pragma unroll
            for (int r = 0; r < 4; r++) lacc[r] *= alpha[r];
            // PV + row-sum (ones column)
#pragma unroll
            for (int ks = 0; ks < 2; ks++) {
                short8 pf = *(const short8*)&pw[l15 * 68 + ks * 32 + quad * 8];
                lacc = mfma_bf16(pf, ones, lacc);
                const int voff = ((ks * 4 + quad) ^ x7) * 8;
#pragma unroll
                for (int nt2 = 0; nt2 < 4; nt2++) {
                    short8 vf = *(const short8*)&Vs[(nt2 * 16 + l15) * 64 + voff];
                    oacc[nt2] = mfma_bf16(pf, vf, oacc[nt2]);
                }
            }
            __syncthreads();
        }
        // epilogue
#pragma unroll
        for (int r = 0; r < 4; r++) {
            const float inv = 1.0f / lacc[r];
            const int s = qt * 64 + wave * 16 + quad * 4 + r;
#pragma unroll
            for (int nt2 = 0; nt2 < 4; nt2++)
                Oc[((size_t)(b * S_LEN + s)) * DM + h * 64 + nt2 * 16 + l15] =
                    f2bf(oacc[nt2][r] * inv);
        }
    }
}

// ---------- workspace layout (u16 elements) ----------
#define OFF_XBF  ((size_t)0)
#define OFF_WCAT ((size_t)8388608)
#define OFF_WO   ((size_t)11534336)
#define OFF_QB   ((size_t)12582912)
#define OFF_KB   ((size_t)20971520)
#define OFF_VT   ((size_t)29360128)

extern "C" void kernel_launch(void* const* d_in, const int* in_sizes, int n_in,
                              void* d_out, int out_size, void* d_ws, size_t ws_size,
                              hipStream_t stream) {
    const float* x  = (const float*)d_in[0];
    const float* Wq = (const float*)d_in[1];
    const float* Wk = (const float*)d_in[2];
    const float* Wv = (const float*)d_in[3];
    const float* Wo = (const float*)d_in[4];
    u16* ws  = (u16*)d_ws;
    u16* XBF = ws + OFF_XBF;
    u16* WCA = ws + OFF_WCAT;
    u16* WOB = ws + OFF_WO;
    u16* QB  = ws + OFF_QB;
    u16* KB  = ws + OFF_KB;
    u16* VT  = ws + OFF_VT;
    u16* AT  = XBF;   // reuse

    cvt_bf16_v4<<<8192, 256, 0, stream>>>((const float4*)x,  (uint2*)XBF, 2097152);
    cvt_bf16_v4<<<1024, 256, 0, stream>>>((const float4*)Wq, (uint2*)(WCA),            262144);
    cvt_bf16_v4<<<1024, 256, 0, stream>>>((const float4*)Wk, (uint2*)(WCA + 1048576),  262144);
    cvt_bf16_v4<<<1024, 256, 0, stream>>>((const float4*)Wv, (uint2*)(WCA + 2097152),  262144);
    cvt_bf16_v4<<<1024, 256, 0, stream>>>((const float4*)Wo, (uint2*)WOB, 262144);

    gemm_nt<0><<<dim3(24, 64), 256, 0, stream>>>(XBF, WCA, QB, KB, VT, nullptr);
    rope_qk<<<32768, 256, 0, stream>>>(QB, KB);
    flash_attn<<<dim3(16, 64), 256, 0, stream>>>(QB, KB, VT, AT);
    gemm_nt<1><<<dim3(8, 64), 256, 0, stream>>>(AT, WOB, nullptr, nullptr, nullptr,
                                                (float*)d_out);
}